// Round 4
// baseline (375.248 us; speedup 1.0000x reference)
//
#include <hip/hip_runtime.h>
#include <hip/hip_bf16.h>

namespace {
constexpr int B = 64, L = 1024, D = 64;
constexpr int PSTRIDE = 40;  // bf16; 80 B rows keep b128 reads 16B-aligned

typedef float f32x4 __attribute__((ext_vector_type(4)));
typedef int   i32x4 __attribute__((ext_vector_type(4)));
typedef __bf16 bf16x8 __attribute__((ext_vector_type(8)));

__device__ inline bf16x8 cvt8(f32x4 a, f32x4 b) {
  bf16x8 r;
  r[0] = (__bf16)a[0]; r[1] = (__bf16)a[1]; r[2] = (__bf16)a[2]; r[3] = (__bf16)a[3];
  r[4] = (__bf16)b[0]; r[5] = (__bf16)b[1]; r[6] = (__bf16)b[2]; r[7] = (__bf16)b[3];
  return r;
}
}  // namespace

// Prep: VT[b][d][q] = bf16(V[b][q][d]);  QT[b][q][d] = bf16(Q[b][q][d] / 8).
// One block per (b, 64-q tile).
__global__ __launch_bounds__(256)
void prep_kernel(const float* __restrict__ qp, const float* __restrict__ vp,
                 __bf16* __restrict__ qt, __bf16* __restrict__ vt) {
  __shared__ float t[64][65];
  const int tid = threadIdx.x;
  const int b = blockIdx.y;
  const int qb = blockIdx.x * 64;

  {  // V tile -> LDS (f32, padded)
    const int qr = tid >> 4, d0 = (tid & 15) * 4;
#pragma unroll
    for (int p = 0; p < 4; ++p) {
      f32x4 r = *reinterpret_cast<const f32x4*>(
          vp + ((size_t)(b * L + qb + p * 16 + qr)) * D + d0);
      *reinterpret_cast<f32x4*>(&t[p * 16 + qr][d0]) = r;
    }
  }
  {  // Q convert in-place layout (scaled by 1/8)
    const int qr = tid >> 2, quad = tid & 3;
    const float* src = qp + ((size_t)(b * L + qb + qr)) * D + quad * 16;
    __bf16* dst = qt + (((size_t)(b * L + qb + qr)) << 6) + quad * 16;
#pragma unroll
    for (int h = 0; h < 2; ++h) {
      f32x4 a = *reinterpret_cast<const f32x4*>(src + h * 8);
      f32x4 bb = *reinterpret_cast<const f32x4*>(src + h * 8 + 4);
      a *= 0.125f; bb *= 0.125f;
      *reinterpret_cast<bf16x8*>(dst + h * 8) = cvt8(a, bb);
    }
  }
  __syncthreads();
  {  // transposed V out: VT rows = d, contiguous q
    const int qh = tid & 7, dr = tid >> 3;  // dr in 0..31
#pragma unroll
    for (int p = 0; p < 2; ++p) {
      const int d = p * 32 + dr;
      f32x4 x, y;
#pragma unroll
      for (int j = 0; j < 4; ++j) x[j] = t[qh * 8 + j][d];
#pragma unroll
      for (int j = 0; j < 4; ++j) y[j] = t[qh * 8 + 4 + j][d];
      *reinterpret_cast<bf16x8*>(vt + (((size_t)(b * D + d)) << 10) + qb + qh * 8) =
          cvt8(x, y);
    }
  }
}

// Main: block = 32 keys (2 waves x 16 k), one batch. NO barriers: P^T per-wave
// in LDS (double-buffered); V/Q read as prepped bf16 (L2-resident); gate/mask
// non-temporal, prefetched one full step ahead; attn stored non-temporal.
__global__ __launch_bounds__(128, 4)
void gated_attn_kernel(const __bf16* __restrict__ qt,
                       const float* __restrict__ kp,
                       const __bf16* __restrict__ vt,
                       const int* __restrict__ mask,
                       const float* __restrict__ gate,
                       float* __restrict__ out_o,
                       float* __restrict__ out_attn) {
  __shared__ __bf16 pt[2][2][16 * PSTRIDE];

  const int tid = threadIdx.x, wave = tid >> 6, lane = tid & 63;
  const int c = lane & 15, g = lane >> 4;
  const int b = blockIdx.y;
  const int kbase = blockIdx.x * 32 + wave * 16;

  // K fragments, loop-invariant (Q side carries the 1/8 scale)
  const float* krow = kp + ((size_t)(b * L + kbase + c)) * D + g * 8;
  const bf16x8 kf0 = cvt8(*reinterpret_cast<const f32x4*>(krow),
                          *reinterpret_cast<const f32x4*>(krow + 4));
  const bf16x8 kf1 = cvt8(*reinterpret_cast<const f32x4*>(krow + 32),
                          *reinterpret_cast<const f32x4*>(krow + 36));

  f32x4 acc[4] = {};  // O[k = kbase+g*4+i][d = t*16+c]

  bf16x8 qf[4];
  f32x4 gg[2]; i32x4 mm[2];

  auto load_q = [&](int qq, bf16x8* dst) {
#pragma unroll
    for (int sub = 0; sub < 2; ++sub) {
      const __bf16* qrow =
          qt + (((size_t)(b * L + qq + sub * 16 + c)) << 6) + g * 8;
      dst[sub * 2 + 0] = *reinterpret_cast<const bf16x8*>(qrow);
      dst[sub * 2 + 1] = *reinterpret_cast<const bf16x8*>(qrow + 32);
    }
  };
  auto load_gm = [&](int qq, f32x4* gd, i32x4* md) {
#pragma unroll
    for (int sub = 0; sub < 2; ++sub) {
      const size_t idx =
          ((size_t)(b * L + qq + sub * 16 + c)) * L + kbase + g * 4;
      gd[sub] = __builtin_nontemporal_load(
          reinterpret_cast<const f32x4*>(gate + idx));
      md[sub] = __builtin_nontemporal_load(
          reinterpret_cast<const i32x4*>(mask + idx));
    }
  };

  load_q(0, qf);
  load_gm(0, gg, mm);

#pragma unroll 2
  for (int qb = 0; qb < L; qb += 32) {
    const int buf = (qb >> 5) & 1;
    const int qn = (qb + 32 < L) ? (qb + 32) : 0;

    // V^T fragments for this step (L2-hot; covered by GEMM1+sigmoid)
    bf16x8 vf[4];
#pragma unroll
    for (int t = 0; t < 4; ++t)
      vf[t] = *reinterpret_cast<const bf16x8*>(
          vt + (((size_t)(b * D + t * 16 + c)) << 10) + qb + g * 8);

    // GEMM1: S^T[16k x 32q]
    f32x4 s[2];
#pragma unroll
    for (int sub = 0; sub < 2; ++sub) {
      f32x4 cc = {};
      cc = __builtin_amdgcn_mfma_f32_16x16x32_bf16(kf0, qf[sub * 2 + 0], cc, 0, 0, 0);
      cc = __builtin_amdgcn_mfma_f32_16x16x32_bf16(kf1, qf[sub * 2 + 1], cc, 0, 0, 0);
      s[sub] = cc;
    }

    // prefetch next-step Q (bf16, L2-hot)
    bf16x8 qfn[4];
    load_q(qn, qfn);

    // sigmoid + attn nt-store + P^T stage (per-wave LDS, no barrier)
    __bf16* myp = &pt[wave][buf][0];
#pragma unroll
    for (int sub = 0; sub < 2; ++sub) {
      const size_t idx =
          ((size_t)(b * L + qb + sub * 16 + c)) * L + kbase + g * 4;
      f32x4 p;
#pragma unroll
      for (int i = 0; i < 4; ++i) {
        const float x = s[sub][i] * gg[sub][i];
        const float e = __expf(-x);
        p[i] = mm[sub][i] ? 0.0f : __builtin_amdgcn_rcpf(1.0f + e);
      }
      __builtin_nontemporal_store(p, reinterpret_cast<f32x4*>(out_attn + idx));
#pragma unroll
      for (int i = 0; i < 4; ++i)
        myp[(g * 4 + i) * PSTRIDE + sub * 16 + c] = (__bf16)p[i];
    }

    // prefetch next-step gate/mask right after consumption: ~full step in flight
    f32x4 gn[2]; i32x4 mn[2];
    load_gm(qn, gn, mn);

    // P^T A-fragment (in-wave lgkmcnt ordering; no cross-wave sharing)
    const bf16x8 pa =
        *reinterpret_cast<const bf16x8*>(&myp[c * PSTRIDE + g * 8]);

    // GEMM2: O += P^T V
#pragma unroll
    for (int t = 0; t < 4; ++t)
      acc[t] = __builtin_amdgcn_mfma_f32_16x16x32_bf16(pa, vf[t], acc[t], 0, 0, 0);

    // rotate prefetch registers
#pragma unroll
    for (int i = 0; i < 4; ++i) qf[i] = qfn[i];
    gg[0] = gn[0]; gg[1] = gn[1];
    mm[0] = mn[0]; mm[1] = mn[1];
  }

  // epilogue
#pragma unroll
  for (int t = 0; t < 4; ++t)
#pragma unroll
    for (int i = 0; i < 4; ++i)
      out_o[((size_t)(b * L + kbase + g * 4 + i)) * D + t * 16 + c] =
          acc[t][i];
}

extern "C" void kernel_launch(void* const* d_in, const int* in_sizes, int n_in,
                              void* d_out, int out_size, void* d_ws, size_t ws_size,
                              hipStream_t stream) {
  const float* q = (const float*)d_in[0];
  const float* k = (const float*)d_in[1];
  const float* v = (const float*)d_in[2];
  const int* mask = (const int*)d_in[3];
  const float* gate = (const float*)d_in[4];

  float* out_o = (float*)d_out;                 // [B, L, D]
  float* out_attn = out_o + (size_t)B * L * D;  // [B, L, L]

  __bf16* qt = (__bf16*)d_ws;                   // [B, L, D] bf16 (scaled 1/8)
  __bf16* vt = qt + (size_t)B * L * D;          // [B, D, L] bf16

  prep_kernel<<<dim3(L / 64, B), dim3(256), 0, stream>>>(q, v, qt, vt);
  gated_attn_kernel<<<dim3(L / 32, B), dim3(128), 0, stream>>>(
      qt, k, vt, mask, gate, out_o, out_attn);
}

// Round 5
// 275.213 us; speedup vs baseline: 1.3635x; 1.3635x over previous
//
#include <hip/hip_runtime.h>
#include <hip/hip_bf16.h>

namespace {
constexpr int B = 64, L = 1024, D = 64;
constexpr int PSTRIDE = 40;  // bf16; 80 B rows keep b128 reads 16B-aligned

typedef float f32x4 __attribute__((ext_vector_type(4)));
typedef int   i32x4 __attribute__((ext_vector_type(4)));
typedef __bf16 bf16x8 __attribute__((ext_vector_type(8)));

__device__ inline bf16x8 cvt8(f32x4 a, f32x4 b) {
  bf16x8 r;
  r[0] = (__bf16)a[0]; r[1] = (__bf16)a[1]; r[2] = (__bf16)a[2]; r[3] = (__bf16)a[3];
  r[4] = (__bf16)b[0]; r[5] = (__bf16)b[1]; r[6] = (__bf16)b[2]; r[7] = (__bf16)b[3];
  return r;
}
}  // namespace

// Prep: VT[b][d][q] = bf16(V[b][q][d]);  QT[b][q][d] = bf16(Q[b][q][d] / 8).
__global__ __launch_bounds__(256)
void prep_kernel(const float* __restrict__ qp, const float* __restrict__ vp,
                 __bf16* __restrict__ qt, __bf16* __restrict__ vt) {
  __shared__ float t[64][65];
  const int tid = threadIdx.x;
  const int b = blockIdx.y;
  const int qb = blockIdx.x * 64;

  {  // V tile -> LDS (f32, padded)
    const int qr = tid >> 4, d0 = (tid & 15) * 4;
#pragma unroll
    for (int p = 0; p < 4; ++p) {
      f32x4 r = *reinterpret_cast<const f32x4*>(
          vp + ((size_t)(b * L + qb + p * 16 + qr)) * D + d0);
      *reinterpret_cast<f32x4*>(&t[p * 16 + qr][d0]) = r;
    }
  }
  {  // Q convert (scaled by 1/8)
    const int qr = tid >> 2, quad = tid & 3;
    const float* src = qp + ((size_t)(b * L + qb + qr)) * D + quad * 16;
    __bf16* dst = qt + (((size_t)(b * L + qb + qr)) << 6) + quad * 16;
#pragma unroll
    for (int h = 0; h < 2; ++h) {
      f32x4 a = *reinterpret_cast<const f32x4*>(src + h * 8);
      f32x4 bb = *reinterpret_cast<const f32x4*>(src + h * 8 + 4);
      a *= 0.125f; bb *= 0.125f;
      *reinterpret_cast<bf16x8*>(dst + h * 8) = cvt8(a, bb);
    }
  }
  __syncthreads();
  {  // transposed V out: VT rows = d, contiguous q
    const int qh = tid & 7, dr = tid >> 3;  // dr in 0..31
#pragma unroll
    for (int p = 0; p < 2; ++p) {
      const int d = p * 32 + dr;
      f32x4 x, y;
#pragma unroll
      for (int j = 0; j < 4; ++j) x[j] = t[qh * 8 + j][d];
#pragma unroll
      for (int j = 0; j < 4; ++j) y[j] = t[qh * 8 + 4 + j][d];
      *reinterpret_cast<bf16x8*>(vt + (((size_t)(b * D + d)) << 10) + qb + qh * 8) =
          cvt8(x, y);
    }
  }
}

// Main: block = 64 keys (4 waves x 16 k), one batch, 1024 blocks. No barriers
// (P^T per-wave in LDS, double-buffered). gate/mask prefetched TWO 32-q steps
// ahead (two named register sets, static indexing); Q one step ahead. All
// loads default-cached (L3 retention across replays matters).
__global__ __launch_bounds__(256)
void gated_attn_kernel(const __bf16* __restrict__ qt,
                       const float* __restrict__ kp,
                       const __bf16* __restrict__ vt,
                       const int* __restrict__ mask,
                       const float* __restrict__ gate,
                       float* __restrict__ out_o,
                       float* __restrict__ out_attn) {
  __shared__ __bf16 pt[4][2][16 * PSTRIDE];  // 10 KiB

  const int tid = threadIdx.x, wave = tid >> 6, lane = tid & 63;
  const int c = lane & 15, g = lane >> 4;
  const int b = blockIdx.y;
  const int kbase = blockIdx.x * 64 + wave * 16;

  // K fragments, loop-invariant (Q side carries the 1/8 scale)
  const float* krow = kp + ((size_t)(b * L + kbase + c)) * D + g * 8;
  const bf16x8 kf0 = cvt8(*reinterpret_cast<const f32x4*>(krow),
                          *reinterpret_cast<const f32x4*>(krow + 4));
  const bf16x8 kf1 = cvt8(*reinterpret_cast<const f32x4*>(krow + 32),
                          *reinterpret_cast<const f32x4*>(krow + 36));

  f32x4 acc[4] = {};  // O[k = kbase+g*4+i][d = t*16+c]

  auto load_q = [&](int qq, bf16x8* dst) {
#pragma unroll
    for (int sub = 0; sub < 2; ++sub) {
      const __bf16* qrow =
          qt + (((size_t)(b * L + qq + sub * 16 + c)) << 6) + g * 8;
      dst[sub * 2 + 0] = *reinterpret_cast<const bf16x8*>(qrow);
      dst[sub * 2 + 1] = *reinterpret_cast<const bf16x8*>(qrow + 32);
    }
  };
  auto load_gm = [&](int qq, f32x4* gd, i32x4* md) {
#pragma unroll
    for (int sub = 0; sub < 2; ++sub) {
      const size_t idx =
          ((size_t)(b * L + qq + sub * 16 + c)) * L + kbase + g * 4;
      gd[sub] = *reinterpret_cast<const f32x4*>(gate + idx);
      md[sub] = *reinterpret_cast<const i32x4*>(mask + idx);
    }
  };

  bf16x8 qfA[4], qfB[4];
  f32x4 ggA[2], ggB[2];
  i32x4 mmA[2], mmB[2];
  load_gm(0, ggA, mmA);   // issue the cold HBM streams first
  load_gm(32, ggB, mmB);
  load_q(0, qfA);
  load_q(32, qfB);

  // one 32-q step; qf/gg/mm are this step's (ready) sets, refilled for q0+64
  auto step = [&](int q0, int buf, bf16x8* qf, f32x4* gg, i32x4* mm) {
    const int qpf = (q0 + 64 < L) ? q0 + 64 : 0;

    // V^T fragments (L2-hot; covered by GEMM1 + sigmoid)
    bf16x8 vf[4];
#pragma unroll
    for (int t = 0; t < 4; ++t)
      vf[t] = *reinterpret_cast<const bf16x8*>(
          vt + (((size_t)(b * D + t * 16 + c)) << 10) + q0 + g * 8);

    // GEMM1: S^T[16k x 32q]
    f32x4 s[2];
#pragma unroll
    for (int sub = 0; sub < 2; ++sub) {
      f32x4 cc = {};
      cc = __builtin_amdgcn_mfma_f32_16x16x32_bf16(kf0, qf[sub * 2 + 0], cc, 0, 0, 0);
      cc = __builtin_amdgcn_mfma_f32_16x16x32_bf16(kf1, qf[sub * 2 + 1], cc, 0, 0, 0);
      s[sub] = cc;
    }

    load_q(qpf, qf);  // refill Q set (L2-hot)

    // sigmoid + attn store + P^T stage (per-wave LDS, no barrier)
    __bf16* myp = &pt[wave][buf][0];
#pragma unroll
    for (int sub = 0; sub < 2; ++sub) {
      const size_t idx =
          ((size_t)(b * L + q0 + sub * 16 + c)) * L + kbase + g * 4;
      f32x4 p;
#pragma unroll
      for (int i = 0; i < 4; ++i) {
        const float x = s[sub][i] * gg[sub][i];
        const float e = __expf(-x);
        p[i] = mm[sub][i] ? 0.0f : __builtin_amdgcn_rcpf(1.0f + e);
      }
      *reinterpret_cast<f32x4*>(out_attn + idx) = p;
#pragma unroll
      for (int i = 0; i < 4; ++i)
        myp[(g * 4 + i) * PSTRIDE + sub * 16 + c] = (__bf16)p[i];
    }

    load_gm(qpf, gg, mm);  // refill gate/mask set: ~2 steps of cover

    const bf16x8 pa =
        *reinterpret_cast<const bf16x8*>(&myp[c * PSTRIDE + g * 8]);

    // GEMM2: O += P^T V
#pragma unroll
    for (int t = 0; t < 4; ++t)
      acc[t] = __builtin_amdgcn_mfma_f32_16x16x32_bf16(pa, vf[t], acc[t], 0, 0, 0);
  };

  for (int qb = 0; qb < L; qb += 64) {
    step(qb,      0, qfA, ggA, mmA);
    step(qb + 32, 1, qfB, ggB, mmB);
  }

  // epilogue
#pragma unroll
  for (int t = 0; t < 4; ++t)
#pragma unroll
    for (int i = 0; i < 4; ++i)
      out_o[((size_t)(b * L + kbase + g * 4 + i)) * D + t * 16 + c] =
          acc[t][i];
}

extern "C" void kernel_launch(void* const* d_in, const int* in_sizes, int n_in,
                              void* d_out, int out_size, void* d_ws, size_t ws_size,
                              hipStream_t stream) {
  const float* q = (const float*)d_in[0];
  const float* k = (const float*)d_in[1];
  const float* v = (const float*)d_in[2];
  const int* mask = (const int*)d_in[3];
  const float* gate = (const float*)d_in[4];

  float* out_o = (float*)d_out;                 // [B, L, D]
  float* out_attn = out_o + (size_t)B * L * D;  // [B, L, L]

  __bf16* qt = (__bf16*)d_ws;                   // [B, L, D] bf16 (scaled 1/8)
  __bf16* vt = qt + (size_t)B * L * D;          // [B, D, L] bf16

  prep_kernel<<<dim3(L / 64, B), dim3(256), 0, stream>>>(q, v, qt, vt);
  gated_attn_kernel<<<dim3(L / 64, B), dim3(256), 0, stream>>>(
      qt, k, vt, mask, gate, out_o, out_attn);
}